// Round 12
// baseline (763.960 us; speedup 1.0000x reference)
//
#include <hip/hip_runtime.h>
#include <hip/hip_fp8.h>
#include <math.h>

#define N_NODES 100000
#define N_EDGES 1250000
#define IN_DIM 12
#define HID 64
#define N_LAYERS 3
#define LN_EPS 1e-5f
#define SLOPE 0.01f

#define NODE_BLOCKS ((N_NODES + 3) / 4)     // 4 waves (nodes) per 256-thread block
#define MFMA_BLOCKS2 ((N_NODES + 127) / 128)    // 128 nodes per 256-thread block (2 tiles)
#define OUT_BLOCKS ((N_NODES + 63) / 64)
#define NEDGE_BLOCKS ((N_NODES + 255) / 256)    // node-parallel edge pass

#define BUCKETS 256
#define BUCKET_NODES 391                         // 256*391 = 100096 >= N_NODES
#define P1_EDGES 4096
#define P1_BLOCKS ((N_EDGES + P1_EDGES - 1) / P1_EDGES)  // 306

typedef short bf16x8 __attribute__((ext_vector_type(8)));
typedef float f32x4 __attribute__((ext_vector_type(4)));
typedef float f32x2 __attribute__((ext_vector_type(2)));

#if defined(__has_builtin)
#if __has_builtin(__builtin_amdgcn_cvt_pk_f32_fp8)
#define HAVE_PK_FP8 1
#endif
#endif

static __device__ __forceinline__ unsigned short f2bf(float f) {
  union { float f; unsigned int u; } v; v.f = f;
  unsigned int r = v.u + 0x7FFFu + ((v.u >> 16) & 1u);   // RNE
  return (unsigned short)(r >> 16);
}
static __device__ __forceinline__ unsigned char f2e4(float f) {
  return __hip_fp8_e4m3(f).__x;
}
static __device__ __forceinline__ float e42f(unsigned char b) {
  __hip_fp8_e4m3 d; d.__x = b;
  return (float)d;
}
// monotone float<->uint keys for atomicMax on signed floats
static __device__ __forceinline__ unsigned keyenc(float f) {
  unsigned u = __float_as_uint(f);
  return (u & 0x80000000u) ? ~u : (u | 0x80000000u);
}
static __device__ __forceinline__ float keydec(unsigned k) {
  unsigned u = (k & 0x80000000u) ? (k ^ 0x80000000u) : ~k;
  return __uint_as_float(u);
}

// ---------------- input projection: h = x @ in_W + in_b ----------------
__global__ void k_in_proj(const float* __restrict__ x,
                          const float* __restrict__ W,   // [12][64]
                          const float* __restrict__ b,
                          float* __restrict__ h) {
  __shared__ float sW[IN_DIM * HID];
  for (int i = threadIdx.x; i < IN_DIM * HID; i += blockDim.x) sW[i] = W[i];
  __syncthreads();
  int wave = threadIdx.x >> 6, lane = threadIdx.x & 63;
  int n = blockIdx.x * 4 + wave;
  if (n >= N_NODES) return;
  float acc = b[lane];
#pragma unroll
  for (int k = 0; k < IN_DIM; ++k)
    acc += x[n * IN_DIM + k] * sW[k * HID + lane];
  h[n * HID + lane] = acc;
}

// ---------------- bucket-level histogram (LDS; 256 global atomics per block) ----------------
__global__ void k_bhist(const int* __restrict__ ei, unsigned* __restrict__ bcnt) {
  __shared__ unsigned cnt[BUCKETS];
  int t = threadIdx.x;
  cnt[t] = 0;
  __syncthreads();
  int base = blockIdx.x * P1_EDGES;
#pragma unroll
  for (int i = 0; i < 16; ++i) {
    int e = base + i * 256 + t;
    if (e < N_EDGES) atomicAdd(&cnt[(unsigned)ei[e] / BUCKET_NODES], 1u);
  }
  __syncthreads();
  if (cnt[t]) atomicAdd(&bcnt[t], cnt[t]);
}

// 1-block scan of bucket counts -> boffs[257]; seed gbcur; rowptr sentinel
__global__ void k_bscan(const unsigned* __restrict__ bcnt,
                        unsigned* __restrict__ boffs,
                        unsigned* __restrict__ gbcur,
                        int* __restrict__ rowptr) {
  __shared__ unsigned sm[BUCKETS];
  int t = threadIdx.x;
  unsigned v = bcnt[t];
  sm[t] = v;
  __syncthreads();
  for (int st = 1; st < BUCKETS; st <<= 1) {
    unsigned tv = (t >= st) ? sm[t - st] : 0u;
    __syncthreads();
    sm[t] += tv;
    __syncthreads();
  }
  unsigned excl = sm[t] - v;
  boffs[t] = excl;
  gbcur[t] = excl;
  if (t == 0) {
    boffs[BUCKETS] = N_EDGES;
    rowptr[N_NODES] = N_EDGES;
  }
}

// pass 1: LDS-binned burst scatter of 8B records (row | col | ew15) into bucket regions
__global__ void k_fill_p1(const int* __restrict__ ei, const float* __restrict__ ew,
                          unsigned* __restrict__ gbcur,
                          unsigned long long* __restrict__ tmp) {
  __shared__ unsigned cnt[BUCKETS], gbase[BUCKETS], lofs[BUCKETS];
  int t = threadIdx.x;
  cnt[t] = 0;
  __syncthreads();
  int base = blockIdx.x * P1_EDGES;
#pragma unroll
  for (int i = 0; i < 16; ++i) {
    int e = base + i * 256 + t;
    if (e < N_EDGES) atomicAdd(&cnt[(unsigned)ei[e] / BUCKET_NODES], 1u);
  }
  __syncthreads();
  {
    unsigned c = cnt[t];
    gbase[t] = c ? atomicAdd(&gbcur[t], c) : 0u;
    lofs[t] = 0;
  }
  __syncthreads();
#pragma unroll
  for (int i = 0; i < 16; ++i) {
    int e = base + i * 256 + t;
    if (e < N_EDGES) {
      unsigned r = (unsigned)ei[e], c = (unsigned)ei[N_EDGES + e];
      // 15-bit float encoding of ew (exp8 + mant7, round-to-nearest); ew in [0,1)
      unsigned eb = (__float_as_uint(ew[e]) + 0x8000u) >> 16;
      if (eb > 0x7FFFu) eb = 0x7FFFu;
      unsigned b = r / BUCKET_NODES;
      unsigned idx = atomicAdd(&lofs[b], 1u);
      tmp[gbase[b] + idx] = ((unsigned long long)r << 32)
                          | ((unsigned long long)c << 15) | eb;
    }
  }
}

// pass 2 (512 thr): per-bucket node histogram + scan -> rowptr; exact placement of records
__global__ void k_fill_p2(const unsigned* __restrict__ boffs,
                          const unsigned long long* __restrict__ tmp,
                          int* __restrict__ rowptr,
                          unsigned* __restrict__ packed) {
  __shared__ unsigned lhist[512];
  __shared__ unsigned lcur[512];
  int b = blockIdx.x, t = threadIdx.x;
  int nb0 = b * BUCKET_NODES;
  int nb1 = min(nb0 + BUCKET_NODES, N_NODES);
  int nn = nb1 - nb0;
  int beg = (int)boffs[b];
  int end = (int)boffs[b + 1];

  lhist[t] = 0;
  __syncthreads();
  for (int i = beg + t; i < end; i += 512) {
    int r = (int)(tmp[i] >> 32);
    atomicAdd(&lhist[r - nb0], 1u);
  }
  __syncthreads();
  unsigned degv = lhist[t];
  for (int st = 1; st < 512; st <<= 1) {
    unsigned tv = (t >= st) ? lhist[t - st] : 0u;
    __syncthreads();
    lhist[t] += tv;
    __syncthreads();
  }
  unsigned excl = lhist[t] - degv;
  if (t < nn) rowptr[nb0 + t] = beg + (int)excl;
  lcur[t] = (unsigned)beg + excl;
  __syncthreads();
  for (int i = beg + t; i < end; i += 512) {
    unsigned long long rec = tmp[i];
    int r = (int)(rec >> 32);
    unsigned pos = atomicAdd(&lcur[r - nb0], 1u);
    packed[pos] = (unsigned)(rec & 0xFFFFFFFFu);
  }
}

// ---------------- per-layer u = W @ a  (alpha decomposition) ----------------
__global__ void k_prep(const float* __restrict__ lin_W,  // [3][64][64]
                       const float* __restrict__ lin_b,  // [3][64]
                       const float* __restrict__ att_W,  // [3][128]
                       float* __restrict__ uvec,         // [3][2][64]
                       float* __restrict__ ucst) {       // [3][2]
  int l = blockIdx.x, j = threadIdx.x;
  const float* Wl = lin_W + l * HID * HID;
  const float* a1 = att_W + l * 2 * HID;
  const float* a2 = a1 + HID;
  float s1 = 0.f, s2 = 0.f;
  for (int c = 0; c < HID; ++c) {
    float w = Wl[j * HID + c];
    s1 += w * a1[c];
    s2 += w * a2[c];
  }
  uvec[l * 128 + j] = s1;
  uvec[l * 128 + 64 + j] = s2;
  float t1 = lin_b[l * HID + j] * a1[j];
  float t2 = lin_b[l * HID + j] * a2[j];
#pragma unroll
  for (int off = 32; off > 0; off >>= 1) {
    t1 += __shfl_xor(t1, off, 64);
    t2 += __shfl_xor(t2, off, 64);
  }
  if (j == 0) { ucst[l * 2] = t1; ucst[l * 2 + 1] = t2; }
}

// ---------------- MFMA linear: hl = h@W + b (fp32 + fp8 mirror); alphas + alpha maxes ----
__global__ void k_lin_mfma(const float* __restrict__ h,
                           const float* __restrict__ W,     // [64][64] this layer
                           const float* __restrict__ bias,  // [64]
                           const float* __restrict__ uvec,  // [2][64] this layer
                           const float* __restrict__ ucst,  // [2]
                           float* __restrict__ hl,
                           unsigned char* __restrict__ hl8, // fp8 e4m3 mirror
                           float* __restrict__ alpha1,
                           float* __restrict__ alpha2,
                           unsigned* __restrict__ amaxk) {  // [2] monotone-key max cells
  __shared__ unsigned short Wt[HID * 72];  // Wt[n][k] bf16, row stride 72
  for (int idx = threadIdx.x; idx < HID * HID; idx += 256) {
    int k = idx >> 6, n = idx & 63;
    Wt[n * 72 + k] = f2bf(W[idx]);
  }
  __syncthreads();

  int wave = threadIdx.x >> 6, lane = threadIdx.x & 63;
  int g = lane >> 4, r = lane & 15;

#pragma unroll
  for (int tile = 0; tile < 2; ++tile) {
    int nb = blockIdx.x * 128 + tile * 64 + wave * 16;
    int row = nb + r;
    bool rowok = row < N_NODES;
    if (nb >= N_NODES) break;

    f32x4 f0 = {0,0,0,0}, f1 = {0,0,0,0}, f2v = {0,0,0,0}, f3 = {0,0,0,0};
    if (rowok) {
      const float* hrow = h + (size_t)row * HID;
      f0  = *(const f32x4*)(hrow + g * 8);
      f1  = *(const f32x4*)(hrow + g * 8 + 4);
      f2v = *(const f32x4*)(hrow + 32 + g * 8);
      f3  = *(const f32x4*)(hrow + 32 + g * 8 + 4);
    }
    bf16x8 a0, a1f;
#pragma unroll
    for (int i = 0; i < 4; ++i) {
      a0[i]      = (short)f2bf(f0[i]);
      a0[i + 4]  = (short)f2bf(f1[i]);
      a1f[i]     = (short)f2bf(f2v[i]);
      a1f[i + 4] = (short)f2bf(f3[i]);
    }

    f32x4 acc[4] = {{0,0,0,0},{0,0,0,0},{0,0,0,0},{0,0,0,0}};
#pragma unroll
    for (int nt = 0; nt < 4; ++nt) {
      bf16x8 b0 = *(const bf16x8*)&Wt[(nt * 16 + r) * 72 + g * 8];
      bf16x8 b1 = *(const bf16x8*)&Wt[(nt * 16 + r) * 72 + 32 + g * 8];
      acc[nt] = __builtin_amdgcn_mfma_f32_16x16x32_bf16(a0, b0, acc[nt], 0, 0, 0);
      acc[nt] = __builtin_amdgcn_mfma_f32_16x16x32_bf16(a1f, b1, acc[nt], 0, 0, 0);
    }

    // alphas from fp32 h fragments + wave maxes
    {
      const float* u1 = uvec;
      const float* u2 = uvec + HID;
      f32x4 ua = *(const f32x4*)(u1 + g * 8),      ub = *(const f32x4*)(u1 + g * 8 + 4);
      f32x4 uc = *(const f32x4*)(u1 + 32 + g * 8), ud = *(const f32x4*)(u1 + 32 + g * 8 + 4);
      float p1 = f0[0]*ua[0]+f0[1]*ua[1]+f0[2]*ua[2]+f0[3]*ua[3]
               + f1[0]*ub[0]+f1[1]*ub[1]+f1[2]*ub[2]+f1[3]*ub[3]
               + f2v[0]*uc[0]+f2v[1]*uc[1]+f2v[2]*uc[2]+f2v[3]*uc[3]
               + f3[0]*ud[0]+f3[1]*ud[1]+f3[2]*ud[2]+f3[3]*ud[3];
      ua = *(const f32x4*)(u2 + g * 8);      ub = *(const f32x4*)(u2 + g * 8 + 4);
      uc = *(const f32x4*)(u2 + 32 + g * 8); ud = *(const f32x4*)(u2 + 32 + g * 8 + 4);
      float p2 = f0[0]*ua[0]+f0[1]*ua[1]+f0[2]*ua[2]+f0[3]*ua[3]
               + f1[0]*ub[0]+f1[1]*ub[1]+f1[2]*ub[2]+f1[3]*ub[3]
               + f2v[0]*uc[0]+f2v[1]*uc[1]+f2v[2]*uc[2]+f2v[3]*uc[3]
               + f3[0]*ud[0]+f3[1]*ud[1]+f3[2]*ud[2]+f3[3]*ud[3];
      p1 += __shfl_xor(p1, 16, 64); p1 += __shfl_xor(p1, 32, 64);
      p2 += __shfl_xor(p2, 16, 64); p2 += __shfl_xor(p2, 32, 64);
      float a1v = p1 + ucst[0];
      float a2v = p2 + ucst[1];
      if (g == 0 && rowok) {
        alpha1[row] = a1v;
        alpha2[row] = a2v;
      }
      // wave max over the 16 rows (upper bound for softmax stabilization)
      float m1 = rowok ? a1v : -INFINITY;
      float m2 = rowok ? a2v : -INFINITY;
      m1 = fmaxf(m1, __shfl_xor(m1, 1, 64)); m2 = fmaxf(m2, __shfl_xor(m2, 1, 64));
      m1 = fmaxf(m1, __shfl_xor(m1, 2, 64)); m2 = fmaxf(m2, __shfl_xor(m2, 2, 64));
      m1 = fmaxf(m1, __shfl_xor(m1, 4, 64)); m2 = fmaxf(m2, __shfl_xor(m2, 4, 64));
      m1 = fmaxf(m1, __shfl_xor(m1, 8, 64)); m2 = fmaxf(m2, __shfl_xor(m2, 8, 64));
      if (lane == 0) {
        atomicMax(&amaxk[0], keyenc(m1));
        atomicMax(&amaxk[1], keyenc(m2));
      }
    }

    // store hl (+bias) fp32 + fp8 mirror. D: col = nt*16 + r, node = nb + g*4 + reg
#pragma unroll
    for (int nt = 0; nt < 4; ++nt) {
      float bv = bias[nt * 16 + r];
#pragma unroll
      for (int reg = 0; reg < 4; ++reg) {
        int n2 = nb + g * 4 + reg;
        if (n2 < N_NODES) {
          float v = acc[nt][reg] + bv;
          hl[(size_t)n2 * HID + nt * 16 + r] = v;
          hl8[(size_t)n2 * HID + nt * 16 + r] = f2e4(v);
        }
      }
    }
  }
}

// ---------------- per-layer edge pass (single-pass, bounded M) + fused ticket sum ----------------
// w[p] = exp(leaky(score) - Mbound) * ew ; S = sum exp(leaky(score) - Mbound)
__global__ void k_edge(const int* __restrict__ rowptr,
                       const unsigned* __restrict__ packed,
                       const float* __restrict__ alpha1,
                       const float* __restrict__ alpha2,
                       const float* __restrict__ attB,
                       const unsigned* __restrict__ amaxk,
                       float* __restrict__ wcoef,
                       float* __restrict__ psum,
                       int* __restrict__ counter,
                       float* __restrict__ red) {
  int t = threadIdx.x;
  int n = blockIdx.x * 256 + t;
  float ab = attB[0];
  float M = keydec(amaxk[0]) + keydec(amaxk[1]) + ab;   // uniform upper bound of scores
  float sum = 0.f;
  if (n < N_NODES) {
    float a1 = alpha1[n] + ab;
    int beg = rowptr[n];
    int end = rowptr[n + 1];
    for (int p = beg; p < end; ++p) {
      unsigned u = packed[p];
      float sc = a1 + alpha2[u >> 15];
      sc = sc > 0.f ? sc : SLOPE * sc;
      float e = __expf(sc - M);
      float ewf = __uint_as_float((u & 0x7FFFu) << 16);
      wcoef[p] = e * ewf;
      sum += e;
    }
  }
  __shared__ float ssum[256];
  __shared__ bool last;
  ssum[t] = sum;
  __syncthreads();
  for (int st = 128; st > 0; st >>= 1) {
    if (t < st) ssum[t] += ssum[t + st];
    __syncthreads();
  }
  if (t == 0) {
    psum[blockIdx.x] = ssum[0];
    __threadfence();
    int old = atomicAdd(counter, 1);
    last = (old == (int)gridDim.x - 1);
  }
  __syncthreads();
  if (!last) return;
  __threadfence();
  volatile const float* vps = psum;
  float s2 = 0.f;
  for (int i = t; i < (int)gridDim.x; i += 256) s2 += vps[i];
  __syncthreads();
  ssum[t] = s2;
  __syncthreads();
  for (int st = 128; st > 0; st >>= 1) {
    if (t < st) ssum[t] += ssum[t + st];
    __syncthreads();
  }
  if (t == 0) {
    red[0] = ssum[0];
    *counter = 0;   // self-reset for next layer / replay
  }
}

// ---------------- fused CSR aggregate: 16-edge x 16-lane layout + relu + LN + residual ----
// lane = g*16 + q : edge-subgroup g in [0,4), quarter-row q in [0,16) -> channels q*4..q*4+3
__global__ void k_agg_update(const int* __restrict__ rowptr,
                             const unsigned* __restrict__ packed,
                             const float* __restrict__ w,
                             const float* __restrict__ red,  // [0]=S
                             const float* __restrict__ hl,
                             const unsigned char* __restrict__ hl8,
                             const float* __restrict__ gam,
                             const float* __restrict__ bet,
                             float* __restrict__ h) {
  int wave = threadIdx.x >> 6, lane = threadIdx.x & 63;
  int n = blockIdx.x * 4 + wave;
  if (n >= N_NODES) return;
  int g = lane >> 4, q = lane & 15;
  int beg = rowptr[n];
  int end = rowptr[n + 1];

  float a0 = 0.f, a1 = 0.f, a2 = 0.f, a3 = 0.f;
  for (int k = beg; k < end; k += 16) {
    int ke0 = k + g, ke1 = k + 4 + g, ke2 = k + 8 + g, ke3 = k + 12 + g;
    bool v0 = ke0 < end, v1 = ke1 < end, v2 = ke2 < end, v3 = ke3 < end;
    unsigned u0 = packed[v0 ? ke0 : beg];
    unsigned u1 = packed[v1 ? ke1 : beg];
    unsigned u2 = packed[v2 ? ke2 : beg];
    unsigned u3 = packed[v3 ? ke3 : beg];
    float w0 = v0 ? w[ke0] : 0.f;
    float w1 = v1 ? w[ke1] : 0.f;
    float w2 = v2 ? w[ke2] : 0.f;
    float w3 = v3 ? w[ke3] : 0.f;
    unsigned d0 = *(const unsigned*)(hl8 + (size_t)(u0 >> 15) * HID + q * 4);
    unsigned d1 = *(const unsigned*)(hl8 + (size_t)(u1 >> 15) * HID + q * 4);
    unsigned d2 = *(const unsigned*)(hl8 + (size_t)(u2 >> 15) * HID + q * 4);
    unsigned d3 = *(const unsigned*)(hl8 + (size_t)(u3 >> 15) * HID + q * 4);
#ifdef HAVE_PK_FP8
    f32x2 l0 = __builtin_amdgcn_cvt_pk_f32_fp8((int)d0, 0);
    f32x2 h0 = __builtin_amdgcn_cvt_pk_f32_fp8((int)d0, 1);
    f32x2 l1 = __builtin_amdgcn_cvt_pk_f32_fp8((int)d1, 0);
    f32x2 h1 = __builtin_amdgcn_cvt_pk_f32_fp8((int)d1, 1);
    f32x2 l2 = __builtin_amdgcn_cvt_pk_f32_fp8((int)d2, 0);
    f32x2 h2 = __builtin_amdgcn_cvt_pk_f32_fp8((int)d2, 1);
    f32x2 l3 = __builtin_amdgcn_cvt_pk_f32_fp8((int)d3, 0);
    f32x2 h3 = __builtin_amdgcn_cvt_pk_f32_fp8((int)d3, 1);
    a0 += w0 * l0[0] + w1 * l1[0] + w2 * l2[0] + w3 * l3[0];
    a1 += w0 * l0[1] + w1 * l1[1] + w2 * l2[1] + w3 * l3[1];
    a2 += w0 * h0[0] + w1 * h1[0] + w2 * h2[0] + w3 * h3[0];
    a3 += w0 * h0[1] + w1 * h1[1] + w2 * h2[1] + w3 * h3[1];
#else
    a0 += w0 * e42f(d0 & 0xffu) + w1 * e42f(d1 & 0xffu)
        + w2 * e42f(d2 & 0xffu) + w3 * e42f(d3 & 0xffu);
    a1 += w0 * e42f((d0 >> 8) & 0xffu) + w1 * e42f((d1 >> 8) & 0xffu)
        + w2 * e42f((d2 >> 8) & 0xffu) + w3 * e42f((d3 >> 8) & 0xffu);
    a2 += w0 * e42f((d0 >> 16) & 0xffu) + w1 * e42f((d1 >> 16) & 0xffu)
        + w2 * e42f((d2 >> 16) & 0xffu) + w3 * e42f((d3 >> 16) & 0xffu);
    a3 += w0 * e42f(d0 >> 24) + w1 * e42f(d1 >> 24)
        + w2 * e42f(d2 >> 24) + w3 * e42f(d3 >> 24);
#endif
  }
  // fold edge-subgroups (bits 4,5 of lane)
  a0 += __shfl_xor(a0, 16, 64); a0 += __shfl_xor(a0, 32, 64);
  a1 += __shfl_xor(a1, 16, 64); a1 += __shfl_xor(a1, 32, 64);
  a2 += __shfl_xor(a2, 16, 64); a2 += __shfl_xor(a2, 32, 64);
  a3 += __shfl_xor(a3, 16, 64); a3 += __shfl_xor(a3, 32, 64);

  float inv = 1.0f / red[0];
  f32x4 hlv = *(const f32x4*)(hl + (size_t)n * HID + q * 4);
  float v0 = fmaxf(hlv[0] + a0 * inv, 0.f);
  float v1 = fmaxf(hlv[1] + a1 * inv, 0.f);
  float v2 = fmaxf(hlv[2] + a2 * inv, 0.f);
  float v3 = fmaxf(hlv[3] + a3 * inv, 0.f);

  float ms = v0 + v1 + v2 + v3;
  ms += __shfl_xor(ms, 1, 64); ms += __shfl_xor(ms, 2, 64);
  ms += __shfl_xor(ms, 4, 64); ms += __shfl_xor(ms, 8, 64);
  float m = ms * (1.0f / HID);
  float d0 = v0 - m, d1 = v1 - m, d2 = v2 - m, d3 = v3 - m;
  float vs = d0 * d0 + d1 * d1 + d2 * d2 + d3 * d3;
  vs += __shfl_xor(vs, 1, 64); vs += __shfl_xor(vs, 2, 64);
  vs += __shfl_xor(vs, 4, 64); vs += __shfl_xor(vs, 8, 64);
  float rs = rsqrtf(vs * (1.0f / HID) + LN_EPS);

  if (g == 0) {
    float* hrow = h + (size_t)n * HID + q * 4;
    f32x4 hv = *(const f32x4*)hrow;
    f32x4 gv = *(const f32x4*)(gam + q * 4);
    f32x4 bv = *(const f32x4*)(bet + q * 4);
    f32x4 o;
    o[0] = hv[0] + d0 * rs * gv[0] + bv[0];
    o[1] = hv[1] + d1 * rs * gv[1] + bv[1];
    o[2] = hv[2] + d2 * rs * gv[2] + bv[2];
    o[3] = hv[3] + d3 * rs * gv[3] + bv[3];
    *(f32x4*)hrow = o;
  }
}

// ---------------- output head via MFMA ----------------
__global__ void k_out_mfma(const float* __restrict__ h,
                           const float* __restrict__ W1,  // [64][32]
                           const float* __restrict__ b1,  // [32]
                           const float* __restrict__ W2,  // [32]
                           const float* __restrict__ b2,  // [1]
                           float* __restrict__ out) {
  __shared__ unsigned short W1t[32 * 72];  // W1t[m][k] bf16
  __shared__ float sW2[32];
  for (int idx = threadIdx.x; idx < HID * 32; idx += 256) {
    int k = idx >> 5, m = idx & 31;
    W1t[m * 72 + k] = f2bf(W1[idx]);
  }
  if (threadIdx.x < 32) sW2[threadIdx.x] = W2[threadIdx.x];
  __syncthreads();

  int wave = threadIdx.x >> 6, lane = threadIdx.x & 63;
  int g = lane >> 4, r = lane & 15;
  int nb = blockIdx.x * 64 + wave * 16;
  int row = nb + r;
  bool rowok = row < N_NODES;

  f32x4 f0 = {0,0,0,0}, f1 = {0,0,0,0}, f2v = {0,0,0,0}, f3 = {0,0,0,0};
  if (rowok) {
    const float* hrow = h + (size_t)row * HID;
    f0  = *(const f32x4*)(hrow + g * 8);
    f1  = *(const f32x4*)(hrow + g * 8 + 4);
    f2v = *(const f32x4*)(hrow + 32 + g * 8);
    f3  = *(const f32x4*)(hrow + 32 + g * 8 + 4);
  }
  bf16x8 a0, a1f;
#pragma unroll
  for (int i = 0; i < 4; ++i) {
    a0[i]      = (short)f2bf(f0[i]);
    a0[i + 4]  = (short)f2bf(f1[i]);
    a1f[i]     = (short)f2bf(f2v[i]);
    a1f[i + 4] = (short)f2bf(f3[i]);
  }

  f32x4 acc[2] = {{0,0,0,0},{0,0,0,0}};
#pragma unroll
  for (int mt = 0; mt < 2; ++mt) {
    bf16x8 b0 = *(const bf16x8*)&W1t[(mt * 16 + r) * 72 + g * 8];
    bf16x8 b1v = *(const bf16x8*)&W1t[(mt * 16 + r) * 72 + 32 + g * 8];
    acc[mt] = __builtin_amdgcn_mfma_f32_16x16x32_bf16(a0, b0, acc[mt], 0, 0, 0);
    acc[mt] = __builtin_amdgcn_mfma_f32_16x16x32_bf16(a1f, b1v, acc[mt], 0, 0, 0);
  }

  float part[4];
#pragma unroll
  for (int reg = 0; reg < 4; ++reg) {
    float p = 0.f;
#pragma unroll
    for (int mt = 0; mt < 2; ++mt) {
      float z = acc[mt][reg] + b1[mt * 16 + r];
      p += fmaxf(z, 0.f) * sW2[mt * 16 + r];
    }
    p += __shfl_xor(p, 1, 64);
    p += __shfl_xor(p, 2, 64);
    p += __shfl_xor(p, 4, 64);
    p += __shfl_xor(p, 8, 64);
    part[reg] = p;
  }
  if (r == 0) {
    float bb = b2[0];
#pragma unroll
    for (int reg = 0; reg < 4; ++reg) {
      int n2 = nb + g * 4 + reg;
      if (n2 < N_NODES)
        out[n2] = 1.0f / (1.0f + expf(-(part[reg] + bb)));
    }
  }
}

extern "C" void kernel_launch(void* const* d_in, const int* in_sizes, int n_in,
                              void* d_out, int out_size, void* d_ws, size_t ws_size,
                              hipStream_t stream) {
  const float* x      = (const float*)d_in[0];
  const int*   ei     = (const int*)d_in[1];     // [2][E]
  const float* ew     = (const float*)d_in[2];
  const float* in_W   = (const float*)d_in[3];
  const float* in_b   = (const float*)d_in[4];
  const float* lin_W  = (const float*)d_in[5];   // [3][64][64]
  const float* lin_b  = (const float*)d_in[6];   // [3][64]
  const float* att_W  = (const float*)d_in[7];   // [3][128]
  const float* att_b  = (const float*)d_in[8];   // [3]
  const float* ln_g   = (const float*)d_in[9];   // [3][64]
  const float* ln_b   = (const float*)d_in[10];  // [3][64]
  const float* out1_W = (const float*)d_in[11];  // [64][32]
  const float* out1_b = (const float*)d_in[12];  // [32]
  const float* out2_W = (const float*)d_in[13];  // [32]
  const float* out2_b = (const float*)d_in[14];  // [1]
  float* out = (float*)d_out;

  float* ws = (float*)d_ws;
  float* h            = ws;                         // 6.4M f
  float* hl           = ws + 6400000;               // 6.4M f
  unsigned char* hl8  = (unsigned char*)(ws + 12800000);       // 6.4M bytes
  unsigned long long* tmp = (unsigned long long*)(ws + 14500000);  // 1.25M u64
  unsigned* packed    = (unsigned*)(ws + 17000000); // 1.25M u32
  float* wcoef        = ws + 18250000;              // 1.25M f
  int* rowptr         = (int*)(ws + 19500000);      // N_NODES+1
  int* counter        = (int*)(ws + 19601000);      // 1 int (ticket)
  unsigned* bcnt      = (unsigned*)(counter + 1);   // 256
  unsigned* amaxk     = bcnt + 256;                 // 6 (2 per layer) — memset with counter
  unsigned* boffs     = amaxk + 6;                  // 257
  float* alpha1       = ws + 19702000;
  float* alpha2       = ws + 19803000;
  float* psum         = ws + 19904000;              // 1024
  float* red          = ws + 19908000;              // [0]=S
  float* uvec         = ws + 19909000;              // [3][2][64]
  float* ucst         = ws + 19910000;              // [3][2]
  unsigned* gbcur     = (unsigned*)(ws + 19912000); // 256

  // ---- one-time CSR build (bucketed, no global per-node atomics) ----
  hipMemsetAsync(counter, 0, (1 + 256 + 6) * sizeof(int), stream);  // ticket + bcnt + amaxk
  k_bhist<<<P1_BLOCKS, 256, 0, stream>>>(ei, bcnt);
  k_bscan<<<1, 256, 0, stream>>>(bcnt, boffs, gbcur, rowptr);
  k_fill_p1<<<P1_BLOCKS, 256, 0, stream>>>(ei, ew, gbcur, tmp);
  k_fill_p2<<<BUCKETS, 512, 0, stream>>>(boffs, tmp, rowptr, packed);

  k_prep<<<N_LAYERS, 64, 0, stream>>>(lin_W, lin_b, att_W, uvec, ucst);
  k_in_proj<<<NODE_BLOCKS, 256, 0, stream>>>(x, in_W, in_b, h);

  for (int i = 0; i < N_LAYERS; ++i) {
    k_lin_mfma<<<MFMA_BLOCKS2, 256, 0, stream>>>(h, lin_W + i * HID * HID, lin_b + i * HID,
                                                 uvec + i * 128, ucst + i * 2,
                                                 hl, hl8, alpha1, alpha2, amaxk + 2 * i);
    k_edge<<<NEDGE_BLOCKS, 256, 0, stream>>>(rowptr, packed, alpha1, alpha2,
                                             att_b + i, amaxk + 2 * i,
                                             wcoef, psum, counter, red);
    k_agg_update<<<NODE_BLOCKS, 256, 0, stream>>>(rowptr, packed, wcoef, red,
                                                  hl, hl8, ln_g + i * HID, ln_b + i * HID, h);
  }

  k_out_mfma<<<OUT_BLOCKS, 256, 0, stream>>>(h, out1_W, out1_b, out2_W, out2_b, out);
}

// Round 13
// 378.594 us; speedup vs baseline: 2.0179x; 2.0179x over previous
//
#include <hip/hip_runtime.h>
#include <hip/hip_fp8.h>
#include <math.h>

#define N_NODES 100000
#define N_EDGES 1250000
#define IN_DIM 12
#define HID 64
#define N_LAYERS 3
#define LN_EPS 1e-5f
#define SLOPE 0.01f

#define NODE_BLOCKS ((N_NODES + 3) / 4)     // 4 waves (nodes) per 256-thread block
#define MFMA_BLOCKS2 ((N_NODES + 127) / 128)    // 128 nodes per 256-thread block (2 tiles)
#define OUT_BLOCKS ((N_NODES + 63) / 64)
#define NEDGE_BLOCKS ((N_NODES + 255) / 256)    // node-parallel edge pass
#define AMAX_BLOCKS ((N_NODES + 1023) / 1024)   // 98

#define BUCKETS 256
#define BUCKET_NODES 391                         // 256*391 = 100096 >= N_NODES
#define P1_EDGES 4096
#define P1_BLOCKS ((N_EDGES + P1_EDGES - 1) / P1_EDGES)  // 306

typedef short bf16x8 __attribute__((ext_vector_type(8)));
typedef float f32x4 __attribute__((ext_vector_type(4)));
typedef float f32x2 __attribute__((ext_vector_type(2)));

#if defined(__has_builtin)
#if __has_builtin(__builtin_amdgcn_cvt_pk_f32_fp8)
#define HAVE_PK_FP8 1
#endif
#endif

static __device__ __forceinline__ unsigned short f2bf(float f) {
  union { float f; unsigned int u; } v; v.f = f;
  unsigned int r = v.u + 0x7FFFu + ((v.u >> 16) & 1u);   // RNE
  return (unsigned short)(r >> 16);
}
static __device__ __forceinline__ unsigned char f2e4(float f) {
  return __hip_fp8_e4m3(f).__x;
}
static __device__ __forceinline__ float e42f(unsigned char b) {
  __hip_fp8_e4m3 d; d.__x = b;
  return (float)d;
}
// monotone float<->uint keys for atomicMax on signed floats
static __device__ __forceinline__ unsigned keyenc(float f) {
  unsigned u = __float_as_uint(f);
  return (u & 0x80000000u) ? ~u : (u | 0x80000000u);
}
static __device__ __forceinline__ float keydec(unsigned k) {
  unsigned u = (k & 0x80000000u) ? (k ^ 0x80000000u) : ~k;
  return __uint_as_float(u);
}

// ---------------- input projection: h = x @ in_W + in_b ----------------
__global__ void k_in_proj(const float* __restrict__ x,
                          const float* __restrict__ W,   // [12][64]
                          const float* __restrict__ b,
                          float* __restrict__ h) {
  __shared__ float sW[IN_DIM * HID];
  for (int i = threadIdx.x; i < IN_DIM * HID; i += blockDim.x) sW[i] = W[i];
  __syncthreads();
  int wave = threadIdx.x >> 6, lane = threadIdx.x & 63;
  int n = blockIdx.x * 4 + wave;
  if (n >= N_NODES) return;
  float acc = b[lane];
#pragma unroll
  for (int k = 0; k < IN_DIM; ++k)
    acc += x[n * IN_DIM + k] * sW[k * HID + lane];
  h[n * HID + lane] = acc;
}

// ---------------- bucket-level histogram (LDS; 256 global atomics per block) ----------------
__global__ void k_bhist(const int* __restrict__ ei, unsigned* __restrict__ bcnt) {
  __shared__ unsigned cnt[BUCKETS];
  int t = threadIdx.x;
  cnt[t] = 0;
  __syncthreads();
  int base = blockIdx.x * P1_EDGES;
#pragma unroll
  for (int i = 0; i < 16; ++i) {
    int e = base + i * 256 + t;
    if (e < N_EDGES) atomicAdd(&cnt[(unsigned)ei[e] / BUCKET_NODES], 1u);
  }
  __syncthreads();
  if (cnt[t]) atomicAdd(&bcnt[t], cnt[t]);
}

// 1-block scan of bucket counts -> boffs[257]; seed gbcur; rowptr sentinel
__global__ void k_bscan(const unsigned* __restrict__ bcnt,
                        unsigned* __restrict__ boffs,
                        unsigned* __restrict__ gbcur,
                        int* __restrict__ rowptr) {
  __shared__ unsigned sm[BUCKETS];
  int t = threadIdx.x;
  unsigned v = bcnt[t];
  sm[t] = v;
  __syncthreads();
  for (int st = 1; st < BUCKETS; st <<= 1) {
    unsigned tv = (t >= st) ? sm[t - st] : 0u;
    __syncthreads();
    sm[t] += tv;
    __syncthreads();
  }
  unsigned excl = sm[t] - v;
  boffs[t] = excl;
  gbcur[t] = excl;
  if (t == 0) {
    boffs[BUCKETS] = N_EDGES;
    rowptr[N_NODES] = N_EDGES;
  }
}

// pass 1: LDS-binned burst scatter of 8B records (row | col | ew15) into bucket regions
__global__ void k_fill_p1(const int* __restrict__ ei, const float* __restrict__ ew,
                          unsigned* __restrict__ gbcur,
                          unsigned long long* __restrict__ tmp) {
  __shared__ unsigned cnt[BUCKETS], gbase[BUCKETS], lofs[BUCKETS];
  int t = threadIdx.x;
  cnt[t] = 0;
  __syncthreads();
  int base = blockIdx.x * P1_EDGES;
#pragma unroll
  for (int i = 0; i < 16; ++i) {
    int e = base + i * 256 + t;
    if (e < N_EDGES) atomicAdd(&cnt[(unsigned)ei[e] / BUCKET_NODES], 1u);
  }
  __syncthreads();
  {
    unsigned c = cnt[t];
    gbase[t] = c ? atomicAdd(&gbcur[t], c) : 0u;
    lofs[t] = 0;
  }
  __syncthreads();
#pragma unroll
  for (int i = 0; i < 16; ++i) {
    int e = base + i * 256 + t;
    if (e < N_EDGES) {
      unsigned r = (unsigned)ei[e], c = (unsigned)ei[N_EDGES + e];
      // 15-bit float encoding of ew (exp8 + mant7, round-to-nearest); ew in [0,1)
      unsigned eb = (__float_as_uint(ew[e]) + 0x8000u) >> 16;
      if (eb > 0x7FFFu) eb = 0x7FFFu;
      unsigned b = r / BUCKET_NODES;
      unsigned idx = atomicAdd(&lofs[b], 1u);
      tmp[gbase[b] + idx] = ((unsigned long long)r << 32)
                          | ((unsigned long long)c << 15) | eb;
    }
  }
}

// pass 2 (512 thr): per-bucket node histogram + scan -> rowptr; exact placement of records
__global__ void k_fill_p2(const unsigned* __restrict__ boffs,
                          const unsigned long long* __restrict__ tmp,
                          int* __restrict__ rowptr,
                          unsigned* __restrict__ packed) {
  __shared__ unsigned lhist[512];
  __shared__ unsigned lcur[512];
  int b = blockIdx.x, t = threadIdx.x;
  int nb0 = b * BUCKET_NODES;
  int nb1 = min(nb0 + BUCKET_NODES, N_NODES);
  int nn = nb1 - nb0;
  int beg = (int)boffs[b];
  int end = (int)boffs[b + 1];

  lhist[t] = 0;
  __syncthreads();
  for (int i = beg + t; i < end; i += 512) {
    int r = (int)(tmp[i] >> 32);
    atomicAdd(&lhist[r - nb0], 1u);
  }
  __syncthreads();
  unsigned degv = lhist[t];
  for (int st = 1; st < 512; st <<= 1) {
    unsigned tv = (t >= st) ? lhist[t - st] : 0u;
    __syncthreads();
    lhist[t] += tv;
    __syncthreads();
  }
  unsigned excl = lhist[t] - degv;
  if (t < nn) rowptr[nb0 + t] = beg + (int)excl;
  lcur[t] = (unsigned)beg + excl;
  __syncthreads();
  for (int i = beg + t; i < end; i += 512) {
    unsigned long long rec = tmp[i];
    int r = (int)(rec >> 32);
    unsigned pos = atomicAdd(&lcur[r - nb0], 1u);
    packed[pos] = (unsigned)(rec & 0xFFFFFFFFu);
  }
}

// ---------------- per-layer u = W @ a  (alpha decomposition) ----------------
__global__ void k_prep(const float* __restrict__ lin_W,  // [3][64][64]
                       const float* __restrict__ lin_b,  // [3][64]
                       const float* __restrict__ att_W,  // [3][128]
                       float* __restrict__ uvec,         // [3][2][64]
                       float* __restrict__ ucst) {       // [3][2]
  int l = blockIdx.x, j = threadIdx.x;
  const float* Wl = lin_W + l * HID * HID;
  const float* a1 = att_W + l * 2 * HID;
  const float* a2 = a1 + HID;
  float s1 = 0.f, s2 = 0.f;
  for (int c = 0; c < HID; ++c) {
    float w = Wl[j * HID + c];
    s1 += w * a1[c];
    s2 += w * a2[c];
  }
  uvec[l * 128 + j] = s1;
  uvec[l * 128 + 64 + j] = s2;
  float t1 = lin_b[l * HID + j] * a1[j];
  float t2 = lin_b[l * HID + j] * a2[j];
#pragma unroll
  for (int off = 32; off > 0; off >>= 1) {
    t1 += __shfl_xor(t1, off, 64);
    t2 += __shfl_xor(t2, off, 64);
  }
  if (j == 0) { ucst[l * 2] = t1; ucst[l * 2 + 1] = t2; }
}

// ---------------- MFMA linear: hl = h@W + b (fp32 + fp8 mirror); alphas ----------------
// 2 x 64-node tiles per block, reusing staged W  (NO atomics here — see k_amax)
__global__ void k_lin_mfma(const float* __restrict__ h,
                           const float* __restrict__ W,     // [64][64] this layer
                           const float* __restrict__ bias,  // [64]
                           const float* __restrict__ uvec,  // [2][64] this layer
                           const float* __restrict__ ucst,  // [2]
                           float* __restrict__ hl,
                           unsigned char* __restrict__ hl8, // fp8 e4m3 mirror
                           float* __restrict__ alpha1,
                           float* __restrict__ alpha2) {
  __shared__ unsigned short Wt[HID * 72];  // Wt[n][k] bf16, row stride 72
  for (int idx = threadIdx.x; idx < HID * HID; idx += 256) {
    int k = idx >> 6, n = idx & 63;
    Wt[n * 72 + k] = f2bf(W[idx]);
  }
  __syncthreads();

  int wave = threadIdx.x >> 6, lane = threadIdx.x & 63;
  int g = lane >> 4, r = lane & 15;

#pragma unroll
  for (int tile = 0; tile < 2; ++tile) {
    int nb = blockIdx.x * 128 + tile * 64 + wave * 16;
    int row = nb + r;
    bool rowok = row < N_NODES;
    if (nb >= N_NODES) break;

    f32x4 f0 = {0,0,0,0}, f1 = {0,0,0,0}, f2v = {0,0,0,0}, f3 = {0,0,0,0};
    if (rowok) {
      const float* hrow = h + (size_t)row * HID;
      f0  = *(const f32x4*)(hrow + g * 8);
      f1  = *(const f32x4*)(hrow + g * 8 + 4);
      f2v = *(const f32x4*)(hrow + 32 + g * 8);
      f3  = *(const f32x4*)(hrow + 32 + g * 8 + 4);
    }
    bf16x8 a0, a1f;
#pragma unroll
    for (int i = 0; i < 4; ++i) {
      a0[i]      = (short)f2bf(f0[i]);
      a0[i + 4]  = (short)f2bf(f1[i]);
      a1f[i]     = (short)f2bf(f2v[i]);
      a1f[i + 4] = (short)f2bf(f3[i]);
    }

    f32x4 acc[4] = {{0,0,0,0},{0,0,0,0},{0,0,0,0},{0,0,0,0}};
#pragma unroll
    for (int nt = 0; nt < 4; ++nt) {
      bf16x8 b0 = *(const bf16x8*)&Wt[(nt * 16 + r) * 72 + g * 8];
      bf16x8 b1 = *(const bf16x8*)&Wt[(nt * 16 + r) * 72 + 32 + g * 8];
      acc[nt] = __builtin_amdgcn_mfma_f32_16x16x32_bf16(a0, b0, acc[nt], 0, 0, 0);
      acc[nt] = __builtin_amdgcn_mfma_f32_16x16x32_bf16(a1f, b1, acc[nt], 0, 0, 0);
    }

    // alphas from fp32 h fragments
    {
      const float* u1 = uvec;
      const float* u2 = uvec + HID;
      f32x4 ua = *(const f32x4*)(u1 + g * 8),      ub = *(const f32x4*)(u1 + g * 8 + 4);
      f32x4 uc = *(const f32x4*)(u1 + 32 + g * 8), ud = *(const f32x4*)(u1 + 32 + g * 8 + 4);
      float p1 = f0[0]*ua[0]+f0[1]*ua[1]+f0[2]*ua[2]+f0[3]*ua[3]
               + f1[0]*ub[0]+f1[1]*ub[1]+f1[2]*ub[2]+f1[3]*ub[3]
               + f2v[0]*uc[0]+f2v[1]*uc[1]+f2v[2]*uc[2]+f2v[3]*uc[3]
               + f3[0]*ud[0]+f3[1]*ud[1]+f3[2]*ud[2]+f3[3]*ud[3];
      ua = *(const f32x4*)(u2 + g * 8);      ub = *(const f32x4*)(u2 + g * 8 + 4);
      uc = *(const f32x4*)(u2 + 32 + g * 8); ud = *(const f32x4*)(u2 + 32 + g * 8 + 4);
      float p2 = f0[0]*ua[0]+f0[1]*ua[1]+f0[2]*ua[2]+f0[3]*ua[3]
               + f1[0]*ub[0]+f1[1]*ub[1]+f1[2]*ub[2]+f1[3]*ub[3]
               + f2v[0]*uc[0]+f2v[1]*uc[1]+f2v[2]*uc[2]+f2v[3]*uc[3]
               + f3[0]*ud[0]+f3[1]*ud[1]+f3[2]*ud[2]+f3[3]*ud[3];
      p1 += __shfl_xor(p1, 16, 64); p1 += __shfl_xor(p1, 32, 64);
      p2 += __shfl_xor(p2, 16, 64); p2 += __shfl_xor(p2, 32, 64);
      if (g == 0 && rowok) {
        alpha1[row] = p1 + ucst[0];
        alpha2[row] = p2 + ucst[1];
      }
    }

    // store hl (+bias) fp32 + fp8 mirror. D: col = nt*16 + r, node = nb + g*4 + reg
#pragma unroll
    for (int nt = 0; nt < 4; ++nt) {
      float bv = bias[nt * 16 + r];
#pragma unroll
      for (int reg = 0; reg < 4; ++reg) {
        int n2 = nb + g * 4 + reg;
        if (n2 < N_NODES) {
          float v = acc[nt][reg] + bv;
          hl[(size_t)n2 * HID + nt * 16 + r] = v;
          hl8[(size_t)n2 * HID + nt * 16 + r] = f2e4(v);
        }
      }
    }
  }
}

// ---------------- alpha maxes: block LDS reduce + 2 atomics/block (196 total) ----------------
__global__ void k_amax(const float* __restrict__ alpha1,
                       const float* __restrict__ alpha2,
                       unsigned* __restrict__ amaxk) {
  __shared__ float s1[1024], s2[1024];
  int t = threadIdx.x;
  float m1 = -INFINITY, m2 = -INFINITY;
  for (int i = blockIdx.x * 1024 + t; i < N_NODES; i += gridDim.x * 1024) {
    m1 = fmaxf(m1, alpha1[i]);
    m2 = fmaxf(m2, alpha2[i]);
  }
  s1[t] = m1; s2[t] = m2;
  __syncthreads();
  for (int st = 512; st > 0; st >>= 1) {
    if (t < st) {
      s1[t] = fmaxf(s1[t], s1[t + st]);
      s2[t] = fmaxf(s2[t], s2[t + st]);
    }
    __syncthreads();
  }
  if (t == 0) {
    atomicMax(&amaxk[0], keyenc(s1[0]));
    atomicMax(&amaxk[1], keyenc(s2[0]));
  }
}

// ---------------- per-layer edge pass (single-pass, bounded M) + fused ticket sum ----------------
// w[p] = exp(leaky(score) - Mbound) * ew ; S = sum exp(leaky(score) - Mbound)
__global__ void k_edge(const int* __restrict__ rowptr,
                       const unsigned* __restrict__ packed,
                       const float* __restrict__ alpha1,
                       const float* __restrict__ alpha2,
                       const float* __restrict__ attB,
                       const unsigned* __restrict__ amaxk,
                       float* __restrict__ wcoef,
                       float* __restrict__ psum,
                       int* __restrict__ counter,
                       float* __restrict__ red) {
  int t = threadIdx.x;
  int n = blockIdx.x * 256 + t;
  float ab = attB[0];
  float M = keydec(amaxk[0]) + keydec(amaxk[1]) + ab;   // uniform upper bound of scores
  float sum = 0.f;
  if (n < N_NODES) {
    float a1 = alpha1[n] + ab;
    int beg = rowptr[n];
    int end = rowptr[n + 1];
    for (int p = beg; p < end; ++p) {
      unsigned u = packed[p];
      float sc = a1 + alpha2[u >> 15];
      sc = sc > 0.f ? sc : SLOPE * sc;
      float e = __expf(sc - M);
      float ewf = __uint_as_float((u & 0x7FFFu) << 16);
      wcoef[p] = e * ewf;
      sum += e;
    }
  }
  __shared__ float ssum[256];
  __shared__ bool last;
  ssum[t] = sum;
  __syncthreads();
  for (int st = 128; st > 0; st >>= 1) {
    if (t < st) ssum[t] += ssum[t + st];
    __syncthreads();
  }
  if (t == 0) {
    psum[blockIdx.x] = ssum[0];
    __threadfence();
    int old = atomicAdd(counter, 1);
    last = (old == (int)gridDim.x - 1);
  }
  __syncthreads();
  if (!last) return;
  __threadfence();
  volatile const float* vps = psum;
  float s2 = 0.f;
  for (int i = t; i < (int)gridDim.x; i += 256) s2 += vps[i];
  __syncthreads();
  ssum[t] = s2;
  __syncthreads();
  for (int st = 128; st > 0; st >>= 1) {
    if (t < st) ssum[t] += ssum[t + st];
    __syncthreads();
  }
  if (t == 0) {
    red[0] = ssum[0];
    *counter = 0;   // self-reset for next layer / replay
  }
}

// ---------------- fused CSR aggregate: 16-edge x 16-lane layout + relu + LN + residual ----
// lane = g*16 + q : edge-subgroup g in [0,4), quarter-row q in [0,16) -> channels q*4..q*4+3
__global__ void k_agg_update(const int* __restrict__ rowptr,
                             const unsigned* __restrict__ packed,
                             const float* __restrict__ w,
                             const float* __restrict__ red,  // [0]=S
                             const float* __restrict__ hl,
                             const unsigned char* __restrict__ hl8,
                             const float* __restrict__ gam,
                             const float* __restrict__ bet,
                             float* __restrict__ h) {
  int wave = threadIdx.x >> 6, lane = threadIdx.x & 63;
  int n = blockIdx.x * 4 + wave;
  if (n >= N_NODES) return;
  int g = lane >> 4, q = lane & 15;
  int beg = rowptr[n];
  int end = rowptr[n + 1];

  float a0 = 0.f, a1 = 0.f, a2 = 0.f, a3 = 0.f;
  for (int k = beg; k < end; k += 16) {
    int ke0 = k + g, ke1 = k + 4 + g, ke2 = k + 8 + g, ke3 = k + 12 + g;
    bool v0 = ke0 < end, v1 = ke1 < end, v2 = ke2 < end, v3 = ke3 < end;
    unsigned u0 = packed[v0 ? ke0 : beg];
    unsigned u1 = packed[v1 ? ke1 : beg];
    unsigned u2 = packed[v2 ? ke2 : beg];
    unsigned u3 = packed[v3 ? ke3 : beg];
    float w0 = v0 ? w[ke0] : 0.f;
    float w1 = v1 ? w[ke1] : 0.f;
    float w2 = v2 ? w[ke2] : 0.f;
    float w3 = v3 ? w[ke3] : 0.f;
    unsigned d0 = *(const unsigned*)(hl8 + (size_t)(u0 >> 15) * HID + q * 4);
    unsigned d1 = *(const unsigned*)(hl8 + (size_t)(u1 >> 15) * HID + q * 4);
    unsigned d2 = *(const unsigned*)(hl8 + (size_t)(u2 >> 15) * HID + q * 4);
    unsigned d3 = *(const unsigned*)(hl8 + (size_t)(u3 >> 15) * HID + q * 4);
#ifdef HAVE_PK_FP8
    f32x2 l0 = __builtin_amdgcn_cvt_pk_f32_fp8((int)d0, 0);
    f32x2 h0 = __builtin_amdgcn_cvt_pk_f32_fp8((int)d0, 1);
    f32x2 l1 = __builtin_amdgcn_cvt_pk_f32_fp8((int)d1, 0);
    f32x2 h1 = __builtin_amdgcn_cvt_pk_f32_fp8((int)d1, 1);
    f32x2 l2 = __builtin_amdgcn_cvt_pk_f32_fp8((int)d2, 0);
    f32x2 h2 = __builtin_amdgcn_cvt_pk_f32_fp8((int)d2, 1);
    f32x2 l3 = __builtin_amdgcn_cvt_pk_f32_fp8((int)d3, 0);
    f32x2 h3 = __builtin_amdgcn_cvt_pk_f32_fp8((int)d3, 1);
    a0 += w0 * l0[0] + w1 * l1[0] + w2 * l2[0] + w3 * l3[0];
    a1 += w0 * l0[1] + w1 * l1[1] + w2 * l2[1] + w3 * l3[1];
    a2 += w0 * h0[0] + w1 * h1[0] + w2 * h2[0] + w3 * h3[0];
    a3 += w0 * h0[1] + w1 * h1[1] + w2 * h2[1] + w3 * h3[1];
#else
    a0 += w0 * e42f(d0 & 0xffu) + w1 * e42f(d1 & 0xffu)
        + w2 * e42f(d2 & 0xffu) + w3 * e42f(d3 & 0xffu);
    a1 += w0 * e42f((d0 >> 8) & 0xffu) + w1 * e42f((d1 >> 8) & 0xffu)
        + w2 * e42f((d2 >> 8) & 0xffu) + w3 * e42f((d3 >> 8) & 0xffu);
    a2 += w0 * e42f((d0 >> 16) & 0xffu) + w1 * e42f((d1 >> 16) & 0xffu)
        + w2 * e42f((d2 >> 16) & 0xffu) + w3 * e42f((d3 >> 16) & 0xffu);
    a3 += w0 * e42f(d0 >> 24) + w1 * e42f(d1 >> 24)
        + w2 * e42f(d2 >> 24) + w3 * e42f(d3 >> 24);
#endif
  }
  // fold edge-subgroups (bits 4,5 of lane)
  a0 += __shfl_xor(a0, 16, 64); a0 += __shfl_xor(a0, 32, 64);
  a1 += __shfl_xor(a1, 16, 64); a1 += __shfl_xor(a1, 32, 64);
  a2 += __shfl_xor(a2, 16, 64); a2 += __shfl_xor(a2, 32, 64);
  a3 += __shfl_xor(a3, 16, 64); a3 += __shfl_xor(a3, 32, 64);

  float inv = 1.0f / red[0];
  f32x4 hlv = *(const f32x4*)(hl + (size_t)n * HID + q * 4);
  float v0 = fmaxf(hlv[0] + a0 * inv, 0.f);
  float v1 = fmaxf(hlv[1] + a1 * inv, 0.f);
  float v2 = fmaxf(hlv[2] + a2 * inv, 0.f);
  float v3 = fmaxf(hlv[3] + a3 * inv, 0.f);

  float ms = v0 + v1 + v2 + v3;
  ms += __shfl_xor(ms, 1, 64); ms += __shfl_xor(ms, 2, 64);
  ms += __shfl_xor(ms, 4, 64); ms += __shfl_xor(ms, 8, 64);
  float m = ms * (1.0f / HID);
  float d0 = v0 - m, d1 = v1 - m, d2 = v2 - m, d3 = v3 - m;
  float vs = d0 * d0 + d1 * d1 + d2 * d2 + d3 * d3;
  vs += __shfl_xor(vs, 1, 64); vs += __shfl_xor(vs, 2, 64);
  vs += __shfl_xor(vs, 4, 64); vs += __shfl_xor(vs, 8, 64);
  float rs = rsqrtf(vs * (1.0f / HID) + LN_EPS);

  if (g == 0) {
    float* hrow = h + (size_t)n * HID + q * 4;
    f32x4 hv = *(const f32x4*)hrow;
    f32x4 gv = *(const f32x4*)(gam + q * 4);
    f32x4 bv = *(const f32x4*)(bet + q * 4);
    f32x4 o;
    o[0] = hv[0] + d0 * rs * gv[0] + bv[0];
    o[1] = hv[1] + d1 * rs * gv[1] + bv[1];
    o[2] = hv[2] + d2 * rs * gv[2] + bv[2];
    o[3] = hv[3] + d3 * rs * gv[3] + bv[3];
    *(f32x4*)hrow = o;
  }
}

// ---------------- output head via MFMA ----------------
__global__ void k_out_mfma(const float* __restrict__ h,
                           const float* __restrict__ W1,  // [64][32]
                           const float* __restrict__ b1,  // [32]
                           const float* __restrict__ W2,  // [32]
                           const float* __restrict__ b2,  // [1]
                           float* __restrict__ out) {
  __shared__ unsigned short W1t[32 * 72];  // W1t[m][k] bf16
  __shared__ float sW2[32];
  for (int idx = threadIdx.x; idx < HID * 32; idx += 256) {
    int k = idx >> 5, m = idx & 31;
    W1t[m * 72 + k] = f2bf(W1[idx]);
  }
  if (threadIdx.x < 32) sW2[threadIdx.x] = W2[threadIdx.x];
  __syncthreads();

  int wave = threadIdx.x >> 6, lane = threadIdx.x & 63;
  int g = lane >> 4, r = lane & 15;
  int nb = blockIdx.x * 64 + wave * 16;
  int row = nb + r;
  bool rowok = row < N_NODES;

  f32x4 f0 = {0,0,0,0}, f1 = {0,0,0,0}, f2v = {0,0,0,0}, f3 = {0,0,0,0};
  if (rowok) {
    const float* hrow = h + (size_t)row * HID;
    f0  = *(const f32x4*)(hrow + g * 8);
    f1  = *(const f32x4*)(hrow + g * 8 + 4);
    f2v = *(const f32x4*)(hrow + 32 + g * 8);
    f3  = *(const f32x4*)(hrow + 32 + g * 8 + 4);
  }
  bf16x8 a0, a1f;
#pragma unroll
  for (int i = 0; i < 4; ++i) {
    a0[i]      = (short)f2bf(f0[i]);
    a0[i + 4]  = (short)f2bf(f1[i]);
    a1f[i]     = (short)f2bf(f2v[i]);
    a1f[i + 4] = (short)f2bf(f3[i]);
  }

  f32x4 acc[2] = {{0,0,0,0},{0,0,0,0}};
#pragma unroll
  for (int mt = 0; mt < 2; ++mt) {
    bf16x8 b0 = *(const bf16x8*)&W1t[(mt * 16 + r) * 72 + g * 8];
    bf16x8 b1v = *(const bf16x8*)&W1t[(mt * 16 + r) * 72 + 32 + g * 8];
    acc[mt] = __builtin_amdgcn_mfma_f32_16x16x32_bf16(a0, b0, acc[mt], 0, 0, 0);
    acc[mt] = __builtin_amdgcn_mfma_f32_16x16x32_bf16(a1f, b1v, acc[mt], 0, 0, 0);
  }

  float part[4];
#pragma unroll
  for (int reg = 0; reg < 4; ++reg) {
    float p = 0.f;
#pragma unroll
    for (int mt = 0; mt < 2; ++mt) {
      float z = acc[mt][reg] + b1[mt * 16 + r];
      p += fmaxf(z, 0.f) * sW2[mt * 16 + r];
    }
    p += __shfl_xor(p, 1, 64);
    p += __shfl_xor(p, 2, 64);
    p += __shfl_xor(p, 4, 64);
    p += __shfl_xor(p, 8, 64);
    part[reg] = p;
  }
  if (r == 0) {
    float bb = b2[0];
#pragma unroll
    for (int reg = 0; reg < 4; ++reg) {
      int n2 = nb + g * 4 + reg;
      if (n2 < N_NODES)
        out[n2] = 1.0f / (1.0f + expf(-(part[reg] + bb)));
    }
  }
}

extern "C" void kernel_launch(void* const* d_in, const int* in_sizes, int n_in,
                              void* d_out, int out_size, void* d_ws, size_t ws_size,
                              hipStream_t stream) {
  const float* x      = (const float*)d_in[0];
  const int*   ei     = (const int*)d_in[1];     // [2][E]
  const float* ew     = (const float*)d_in[2];
  const float* in_W   = (const float*)d_in[3];
  const float* in_b   = (const float*)d_in[4];
  const float* lin_W  = (const float*)d_in[5];   // [3][64][64]
  const float* lin_b  = (const float*)d_in[6];   // [3][64]
  const float* att_W  = (const float*)d_in[7];   // [3][128]
  const float* att_b  = (const float*)d_in[8];   // [3]
  const float* ln_g   = (const float*)d_in[9];   // [3][64]
  const float* ln_b   = (const float*)d_in[10];  // [3][64]
  const float* out1_W = (const float*)d_in[11];  // [64][32]
  const float* out1_b = (const float*)d_in[12];  // [32]
  const float* out2_W = (const float*)d_in[13];  // [32]
  const float* out2_b = (const float*)d_in[14];  // [1]
  float* out = (float*)d_out;

  float* ws = (float*)d_ws;
  float* h            = ws;                         // 6.4M f
  float* hl           = ws + 6400000;               // 6.4M f
  unsigned char* hl8  = (unsigned char*)(ws + 12800000);       // 6.4M bytes
  unsigned long long* tmp = (unsigned long long*)(ws + 14500000);  // 1.25M u64
  unsigned* packed    = (unsigned*)(ws + 17000000); // 1.25M u32
  float* wcoef        = ws + 18250000;              // 1.25M f
  int* rowptr         = (int*)(ws + 19500000);      // N_NODES+1
  int* counter        = (int*)(ws + 19601000);      // 1 int (ticket)
  unsigned* bcnt      = (unsigned*)(counter + 1);   // 256
  unsigned* amaxk     = bcnt + 256;                 // 6 (2 per layer) — memset with counter
  unsigned* boffs     = amaxk + 6;                  // 257
  float* alpha1       = ws + 19702000;
  float* alpha2       = ws + 19803000;
  float* psum         = ws + 19904000;              // 1024
  float* red          = ws + 19908000;              // [0]=S
  float* uvec         = ws + 19909000;              // [3][2][64]
  float* ucst         = ws + 19910000;              // [3][2]
  unsigned* gbcur     = (unsigned*)(ws + 19912000); // 256

  // ---- one-time CSR build (bucketed, no global per-node atomics) ----
  hipMemsetAsync(counter, 0, (1 + 256 + 6) * sizeof(int), stream);  // ticket + bcnt + amaxk
  k_bhist<<<P1_BLOCKS, 256, 0, stream>>>(ei, bcnt);
  k_bscan<<<1, 256, 0, stream>>>(bcnt, boffs, gbcur, rowptr);
  k_fill_p1<<<P1_BLOCKS, 256, 0, stream>>>(ei, ew, gbcur, tmp);
  k_fill_p2<<<BUCKETS, 512, 0, stream>>>(boffs, tmp, rowptr, packed);

  k_prep<<<N_LAYERS, 64, 0, stream>>>(lin_W, lin_b, att_W, uvec, ucst);
  k_in_proj<<<NODE_BLOCKS, 256, 0, stream>>>(x, in_W, in_b, h);

  for (int i = 0; i < N_LAYERS; ++i) {
    k_lin_mfma<<<MFMA_BLOCKS2, 256, 0, stream>>>(h, lin_W + i * HID * HID, lin_b + i * HID,
                                                 uvec + i * 128, ucst + i * 2,
                                                 hl, hl8, alpha1, alpha2);
    k_amax<<<AMAX_BLOCKS, 1024, 0, stream>>>(alpha1, alpha2, amaxk + 2 * i);
    k_edge<<<NEDGE_BLOCKS, 256, 0, stream>>>(rowptr, packed, alpha1, alpha2,
                                             att_b + i, amaxk + 2 * i,
                                             wcoef, psum, counter, red);
    k_agg_update<<<NODE_BLOCKS, 256, 0, stream>>>(rowptr, packed, wcoef, red,
                                                  hl, hl8, ln_g + i * HID, ln_b + i * HID, h);
  }

  k_out_mfma<<<OUT_BLOCKS, 256, 0, stream>>>(h, out1_W, out1_b, out2_W, out2_b, out);
}